// Round 9
// baseline (138.262 us; speedup 1.0000x reference)
//
#include <hip/hip_runtime.h>
#include <hip/hip_bf16.h>

typedef __bf16 bf16_t;
typedef __bf16 bf16x8 __attribute__((ext_vector_type(8)));
typedef float  f32x4  __attribute__((ext_vector_type(4)));

#define GLL16(gp, lp) __builtin_amdgcn_global_load_lds(                        \
    (const __attribute__((address_space(1))) unsigned int*)(gp),               \
    (__attribute__((address_space(3))) unsigned int*)(lp), 16, 0, 0)

#define BAR()    asm volatile("s_barrier" ::: "memory")
#define VMCNT0() asm volatile("s_waitcnt vmcnt(0)" ::: "memory")

__device__ __forceinline__ float fast_sigmoid(float x) {
    return 1.f / (1.f + __expf(-x));
}
__device__ __forceinline__ float fast_tanh(float x) {
    float ax = fabsf(x);
    float t  = __expf(-2.f * ax);
    float r  = (1.f - t) / (1.f + t);
    return copysignf(r, x);
}

// ---------------- fused pack kernel: fp32 -> bf16 (A, W-interleaved, V) ----------------
__global__ void pack_all(const float* __restrict__ inp,  const float* __restrict__ hid,
                         const float* __restrict__ wf,   const float* __restrict__ wi,
                         const float* __restrict__ wo,   const float* __restrict__ wc,
                         const float* __restrict__ vw,
                         bf16_t* __restrict__ A, bf16_t* __restrict__ W,
                         bf16_t* __restrict__ V) {
    const size_t NA = (size_t)16384 * 128;      // A chunks (of 8 elems)
    const size_t NW = 262144;                   // W chunks
    const size_t NV = 32768;                    // V chunks
    const size_t total = NA + NW + NV;
    size_t i = (size_t)blockIdx.x * blockDim.x + threadIdx.x;
    const size_t stride = (size_t)gridDim.x * blockDim.x;
    for (; i < total; i += stride) {
        const float* src;
        bf16_t* dst;
        if (i < NA) {
            size_t b = i >> 7;
            int kc = (int)(i & 127);
            src = (kc < 64) ? (inp + b * 512 + kc * 8)
                            : (hid + b * 512 + (kc - 64) * 8);
            dst = A + i * 8;
        } else if (i < NA + NW) {
            size_t idx = i - NA;
            int n  = (int)(idx >> 7);
            int ch = (int)(idx & 127);
            int g  = (n >> 4) & 3;
            int j  = ((n >> 6) << 4) | (n & 15);
            const float* s0 = (g == 0) ? wf : (g == 1) ? wi : (g == 2) ? wo : wc;
            src = s0 + (size_t)j * 1024 + ch * 8;
            dst = W + idx * 8;
        } else {
            size_t idx = i - NA - NW;
            src = vw + idx * 8;
            dst = V + idx * 8;
        }
        float4 f0 = *(const float4*)src;
        float4 f1 = *(const float4*)(src + 4);
        bf16x8 v;
        v[0] = (bf16_t)f0.x; v[1] = (bf16_t)f0.y; v[2] = (bf16_t)f0.z; v[3] = (bf16_t)f0.w;
        v[4] = (bf16_t)f1.x; v[5] = (bf16_t)f1.y; v[6] = (bf16_t)f1.z; v[7] = (bf16_t)f1.w;
        *(bf16x8*)dst = v;
    }
}

// ------- 128x128x64 fused 4-gate GEMM, double-buffered, issue-early staging -------
// r5 geometry (4 waves, 64x64 wave tiles, XOR swizzle) but tile u+1's 8 GLLs
// are issued BEFORE computing tile u; the single vmcnt(0)+barrier then lands
// ~600-900 cyc after issue, hiding most HBM latency (r5 exposed it fully).
// 64 KB LDS -> 2 blocks/CU cover the residue.
__global__ __launch_bounds__(256, 2) void gemm_gates(
        const bf16_t* __restrict__ A,     // [16384][1024]
        const bf16_t* __restrict__ Wp,    // [2048][1024] gate-interleaved
        const float* __restrict__ bF, const float* __restrict__ bI,
        const float* __restrict__ bO, const float* __restrict__ bC,
        const float* __restrict__ cell,   // [16384][512]
        float* __restrict__ out_cell,
        float* __restrict__ out_hid,
        bf16_t* __restrict__ hid_bf) {
    const int tid  = threadIdx.x;
    const int lane = tid & 63;
    const int wid  = tid >> 6;     // 0..3
    const int wm   = wid >> 1;     // 0..1 (M)
    const int wn   = wid & 1;      // 0..1 (N)
    const int l15  = lane & 15;
    const int l16  = lane >> 4;

    // XCD-contiguous swizzle: 2048 wgs RR over 8 XCDs.
    const int w  = blockIdx.x;
    const int s  = (w & 7) * 256 + (w >> 3);
    const int by = s >> 4;   // 0..127
    const int bx = s & 15;   // 0..15

    __shared__ __align__(16) unsigned char sA[2][16384];  // [buf][128 rows][128 B]
    __shared__ __align__(16) unsigned char sB[2][16384];

    f32x4 acc[4][4];  // [m][n-frag==gate]
#pragma unroll
    for (int m = 0; m < 4; ++m)
#pragma unroll
        for (int n = 0; n < 4; ++n) acc[m][n] = f32x4{0.f, 0.f, 0.f, 0.f};

    // staging: thread t covers row (t>>3) of each 32-row quarter q;
    // physical 16B slot t&7 holds logical chunk (t&7)^(row&7).
    const int trow = tid >> 3;                      // 0..31
    const int schk = (tid & 7) ^ (trow & 7);
    const bf16_t* a_base = A  + (size_t)(by * 128 + trow) * 1024 + schk * 8;
    const bf16_t* b_base = Wp + (size_t)(bx * 128 + trow) * 1024 + schk * 8;
    const unsigned ldso = (unsigned)tid * 16;

    auto stage = [&](int v, int d) {   // stage K-chunk v (A and B) into buf d
#pragma unroll
        for (int q = 0; q < 4; ++q)
            GLL16(a_base + (size_t)q * 32768 + v * 64, &sA[d][0] + q * 4096 + ldso);
#pragma unroll
        for (int q = 0; q < 4; ++q)
            GLL16(b_base + (size_t)q * 32768 + v * 64, &sB[d][0] + q * 4096 + ldso);
    };

    // prologue: tile 0 -> buf 0, full drain
    stage(0, 0);
    VMCNT0();
    BAR();

    for (int u = 0; u < 16; ++u) {
        // issue next tile's staging FIRST (into the other buffer; no WAR)
        stage(u < 15 ? u + 1 : 15, (u + 1) & 1);

        const unsigned char* aL = &sA[u & 1][0];
        const unsigned char* bL = &sB[u & 1][0];
#pragma unroll
        for (int kk = 0; kk < 2; ++kk) {
            bf16x8 af[4], bg[4];
#pragma unroll
            for (int m = 0; m < 4; ++m) {
                int r  = wm * 64 + m * 16 + l15;
                int sl = (kk * 4 + l16) ^ (r & 7);
                af[m] = *reinterpret_cast<const bf16x8*>(aL + r * 128 + sl * 16);
            }
#pragma unroll
            for (int n = 0; n < 4; ++n) {
                int r  = wn * 64 + n * 16 + l15;
                int sl = (kk * 4 + l16) ^ (r & 7);
                bg[n] = *reinterpret_cast<const bf16x8*>(bL + r * 128 + sl * 16);
            }
#pragma unroll
            for (int m = 0; m < 4; ++m)
#pragma unroll
                for (int n = 0; n < 4; ++n)
                    acc[m][n] = __builtin_amdgcn_mfma_f32_16x16x32_bf16(af[m], bg[n], acc[m][n], 0, 0, 0);
        }

        VMCNT0();   // next tile staged (issued ~600-900 cyc ago: mostly hidden)
        BAR();      // all waves past their reads of buf[u&1]; GLL handoff safe
    }

    // ---- fused LSTM epilogue; n-frag index IS the gate, j = (bx*2+wn)*16+l15
    const int jj = (bx * 2 + wn) * 16 + l15;
    const float bf_ = bF[jj], bi_ = bI[jj], bo_ = bO[jj], bc_ = bC[jj];
    const int rbase = by * 128 + wm * 64 + l16 * 4;
#pragma unroll
    for (int m = 0; m < 4; ++m) {
#pragma unroll
        for (int e = 0; e < 4; ++e) {
            int row = rbase + m * 16 + e;
            size_t idx = (size_t)row * 512 + jj;
            float fg = fast_sigmoid(acc[m][0][e] + bf_);
            float ig = fast_sigmoid(acc[m][1][e] + bi_);
            float og = fast_sigmoid(acc[m][2][e] + bo_);
            float cg = fast_tanh(acc[m][3][e] + bc_);
            float cs = cell[idx];
            float nc = fg * cs + ig * cg;
            float nh = og * fast_tanh(nc);
            out_cell[idx] = nc;
            out_hid[idx]  = nh;
            hid_bf[idx]   = (bf16_t)nh;
        }
    }
}

// ---------------- output GEMM: out = hid @ V^T + vb ----------------
__global__ void gemm_out(const bf16_t* __restrict__ Ah,   // [16384][512]
                         const bf16_t* __restrict__ V,    // [512][512]
                         const float* __restrict__ vb,
                         float* __restrict__ out) {
    constexpr int K = 512;
    const int tid  = threadIdx.x;
    const int lane = tid & 63;
    const int wid  = tid >> 6;
    const int wm   = wid >> 1;
    const int wn   = wid & 1;
    const int w  = blockIdx.y * 4 + blockIdx.x;
    const int s  = (w & 7) * 64 + (w >> 3);
    const int mtile = (s >> 2) * 128;
    const int ntile = (s & 3) * 128;

    __shared__ __align__(16) unsigned char sA[128 * 64];
    __shared__ __align__(16) unsigned char sB[128 * 64];

    f32x4 acc[4][4];  // [n-frag][m-frag]
#pragma unroll
    for (int n = 0; n < 4; ++n)
#pragma unroll
        for (int m = 0; m < 4; ++m) acc[n][m] = f32x4{0.f, 0.f, 0.f, 0.f};

    const bf16_t* gA[2]; const bf16_t* gB[2];
    unsigned ldsOff[2];
#pragma unroll
    for (int q = 0; q < 2; ++q) {
        int ch = q * 4 + wid;
        int r  = ch * 16 + (lane >> 2);
        int cphys = lane & 3;
        int clog  = cphys ^ ((r >> 1) & 3);
        gA[q] = Ah + (size_t)(mtile + r) * K + clog * 8;
        gB[q] = V  + (size_t)(ntile + r) * K + clog * 8;
        ldsOff[q] = (unsigned)ch * 1024;
    }

    for (int k0 = 0; k0 < K; k0 += 32) {
#pragma unroll
        for (int q = 0; q < 2; ++q) {
            GLL16(gA[q] + k0, sA + ldsOff[q]);
            GLL16(gB[q] + k0, sB + ldsOff[q]);
        }
        __syncthreads();

        bf16x8 af[4], bfv[4];
#pragma unroll
        for (int m = 0; m < 4; ++m) {
            int r = wm * 64 + m * 16 + (lane & 15);
            int c = (lane >> 4) ^ ((r >> 1) & 3);
            af[m] = *reinterpret_cast<const bf16x8*>(sA + r * 64 + c * 16);
        }
#pragma unroll
        for (int n = 0; n < 4; ++n) {
            int r = wn * 64 + n * 16 + (lane & 15);
            int c = (lane >> 4) ^ ((r >> 1) & 3);
            bfv[n] = *reinterpret_cast<const bf16x8*>(sB + r * 64 + c * 16);
        }
#pragma unroll
        for (int n = 0; n < 4; ++n)
#pragma unroll
            for (int m = 0; m < 4; ++m)
                acc[n][m] = __builtin_amdgcn_mfma_f32_16x16x32_bf16(af[m], bfv[n], acc[n][m], 0, 0, 0);
        __syncthreads();
    }

    const int cl = lane & 15;
#pragma unroll
    for (int n = 0; n < 4; ++n) {
        int coln = ntile + wn * 64 + n * 16 + cl;
        float b = vb[coln];
#pragma unroll
        for (int m = 0; m < 4; ++m) {
#pragma unroll
            for (int e = 0; e < 4; ++e) {
                int row = mtile + wm * 64 + m * 16 + (lane >> 4) * 4 + e;
                out[(size_t)row * 512 + coln] = acc[n][m][e] + b;
            }
        }
    }
}

extern "C" void kernel_launch(void* const* d_in, const int* in_sizes, int n_in,
                              void* d_out, int out_size, void* d_ws, size_t ws_size,
                              hipStream_t stream) {
    const float* inputs = (const float*)d_in[0];
    const float* cell   = (const float*)d_in[1];
    const float* hidden = (const float*)d_in[2];
    const float* Wf_w = (const float*)d_in[3];
    const float* Wf_b = (const float*)d_in[4];
    const float* Wi_w = (const float*)d_in[5];
    const float* Wi_b = (const float*)d_in[6];
    const float* Wc_w = (const float*)d_in[7];
    const float* Wc_b = (const float*)d_in[8];
    const float* Wo_w = (const float*)d_in[9];
    const float* Wo_b = (const float*)d_in[10];
    const float* V_w  = (const float*)d_in[11];
    const float* V_b  = (const float*)d_in[12];
    float* out = (float*)d_out;

    char* ws = (char*)d_ws;
    bf16_t* A_bf = (bf16_t*)(ws);                                  // 32 MB
    bf16_t* W_bf = (bf16_t*)(ws + 33554432);                       // 4 MB
    bf16_t* V_bf = (bf16_t*)(ws + 33554432 + 4194304);             // 0.5 MB
    bf16_t* h_bf = (bf16_t*)(ws + 33554432 + 4194304 + 524288);    // 16 MB

    pack_all<<<2048, 256, 0, stream>>>(inputs, hidden, Wf_w, Wi_w, Wo_w, Wc_w,
                                       V_w, A_bf, W_bf, V_bf);

    gemm_gates<<<2048, 256, 0, stream>>>(
        A_bf, W_bf, Wf_b, Wi_b, Wo_b, Wc_b, cell,
        out, out + (size_t)16384 * 512, h_bf);

    gemm_out<<<dim3(4, 128), 256, 0, stream>>>(
        h_bf, V_bf, V_b, out + (size_t)2 * 16384 * 512);
}

// Round 10
// 126.880 us; speedup vs baseline: 1.0897x; 1.0897x over previous
//
#include <hip/hip_runtime.h>
#include <hip/hip_bf16.h>

typedef __bf16 bf16_t;
typedef __bf16 bf16x8 __attribute__((ext_vector_type(8)));
typedef float  f32x4  __attribute__((ext_vector_type(4)));

#define GLL16(gp, lp) __builtin_amdgcn_global_load_lds(                        \
    (const __attribute__((address_space(1))) unsigned int*)(gp),               \
    (__attribute__((address_space(3))) unsigned int*)(lp), 16, 0, 0)

__device__ __forceinline__ float fast_sigmoid(float x) {
    return 1.f / (1.f + __expf(-x));
}
__device__ __forceinline__ float fast_tanh(float x) {
    float ax = fabsf(x);
    float t  = __expf(-2.f * ax);
    float r  = (1.f - t) / (1.f + t);
    return copysignf(r, x);
}

// ---------------- fused pack kernel: fp32 -> bf16 (A, W-interleaved, V) ----------------
// (verbatim r8 — benched: cuts non-gates time from ~39 to ~26.5 us)
__global__ void pack_all(const float* __restrict__ inp,  const float* __restrict__ hid,
                         const float* __restrict__ wf,   const float* __restrict__ wi,
                         const float* __restrict__ wo,   const float* __restrict__ wc,
                         const float* __restrict__ vw,
                         bf16_t* __restrict__ A, bf16_t* __restrict__ W,
                         bf16_t* __restrict__ V) {
    const size_t NA = (size_t)16384 * 128;      // A chunks (of 8 elems)
    const size_t NW = 262144;                   // W chunks
    const size_t NV = 32768;                    // V chunks
    const size_t total = NA + NW + NV;
    size_t i = (size_t)blockIdx.x * blockDim.x + threadIdx.x;
    const size_t stride = (size_t)gridDim.x * blockDim.x;
    for (; i < total; i += stride) {
        const float* src;
        bf16_t* dst;
        if (i < NA) {
            size_t b = i >> 7;
            int kc = (int)(i & 127);
            src = (kc < 64) ? (inp + b * 512 + kc * 8)
                            : (hid + b * 512 + (kc - 64) * 8);
            dst = A + i * 8;
        } else if (i < NA + NW) {
            size_t idx = i - NA;
            int n  = (int)(idx >> 7);
            int ch = (int)(idx & 127);
            int g  = (n >> 4) & 3;
            int j  = ((n >> 6) << 4) | (n & 15);
            const float* s0 = (g == 0) ? wf : (g == 1) ? wi : (g == 2) ? wo : wc;
            src = s0 + (size_t)j * 1024 + ch * 8;
            dst = W + idx * 8;
        } else {
            size_t idx = i - NA - NW;
            src = vw + idx * 8;
            dst = V + idx * 8;
        }
        float4 f0 = *(const float4*)src;
        float4 f1 = *(const float4*)(src + 4);
        bf16x8 v;
        v[0] = (bf16_t)f0.x; v[1] = (bf16_t)f0.y; v[2] = (bf16_t)f0.z; v[3] = (bf16_t)f0.w;
        v[4] = (bf16_t)f1.x; v[5] = (bf16_t)f1.y; v[6] = (bf16_t)f1.z; v[7] = (bf16_t)f1.w;
        *(bf16x8*)dst = v;
    }
}

// ------- 128x128x64 fused 4-gate GEMM (verbatim r5 — best measured: 91.5 us) -------
// 4 waves (2M x 2N), per-wave 64x64, single-buffered 32 KiB LDS, 2-barrier
// K-loop, GLL16 staging, XOR swizzle, XCD-contiguous grid. ~2.75 blocks/CU
// of TLP hide the per-tile drain (m97/m114 mechanism).
__global__ __launch_bounds__(256, 4) void gemm_gates(
        const bf16_t* __restrict__ A,     // [16384][1024]
        const bf16_t* __restrict__ Wp,    // [2048][1024] gate-interleaved
        const float* __restrict__ bF, const float* __restrict__ bI,
        const float* __restrict__ bO, const float* __restrict__ bC,
        const float* __restrict__ cell,   // [16384][512]
        float* __restrict__ out_cell,
        float* __restrict__ out_hid,
        bf16_t* __restrict__ hid_bf) {
    const int tid  = threadIdx.x;
    const int lane = tid & 63;
    const int wid  = tid >> 6;     // 0..3
    const int wm   = wid >> 1;     // 0..1 (M)
    const int wn   = wid & 1;      // 0..1 (N)
    const int l15  = lane & 15;
    const int l16  = lane >> 4;

    // XCD-contiguous swizzle: 2048 wgs RR over 8 XCDs -> XCD x serves
    // s in [x*256, x*256+256): 16 contiguous by-panels x all 16 bx.
    const int w  = blockIdx.x;
    const int s  = (w & 7) * 256 + (w >> 3);
    const int by = s >> 4;   // 0..127
    const int bx = s & 15;   // 0..15

    __shared__ __align__(16) unsigned char sA[128 * 128];  // [row][128 B], swizzled
    __shared__ __align__(16) unsigned char sB[128 * 128];

    f32x4 acc[4][4];  // [m][n-frag==gate]
#pragma unroll
    for (int m = 0; m < 4; ++m)
#pragma unroll
        for (int n = 0; n < 4; ++n) acc[m][n] = f32x4{0.f, 0.f, 0.f, 0.f};

    // staging: thread t covers row (t>>3) of each 32-row quarter q;
    // physical 16B slot t&7 holds logical chunk (t&7)^(row&7).
    const int trow = tid >> 3;                      // 0..31
    const int schk = (tid & 7) ^ (trow & 7);
    const bf16_t* a_base = A  + (size_t)(by * 128 + trow) * 1024 + schk * 8;
    const bf16_t* b_base = Wp + (size_t)(bx * 128 + trow) * 1024 + schk * 8;
    const unsigned ldso = (unsigned)tid * 16;       // linear: lane*16 within wave

    for (int u = 0; u < 16; ++u) {
        const int ko = u * 64;                      // k-offset (elems)
#pragma unroll
        for (int q = 0; q < 4; ++q)
            GLL16(a_base + (size_t)q * 32768 + ko, sA + q * 4096 + ldso);
#pragma unroll
        for (int q = 0; q < 4; ++q)
            GLL16(b_base + (size_t)q * 32768 + ko, sB + q * 4096 + ldso);
        __syncthreads();   // vmcnt(0) drain + barrier: staged tile visible

#pragma unroll
        for (int kk = 0; kk < 2; ++kk) {
            bf16x8 af[4], bg[4];
#pragma unroll
            for (int m = 0; m < 4; ++m) {
                int r  = wm * 64 + m * 16 + l15;
                int sl = (kk * 4 + l16) ^ (r & 7);
                af[m] = *reinterpret_cast<const bf16x8*>(sA + r * 128 + sl * 16);
            }
#pragma unroll
            for (int n = 0; n < 4; ++n) {
                int r  = wn * 64 + n * 16 + l15;
                int sl = (kk * 4 + l16) ^ (r & 7);
                bg[n] = *reinterpret_cast<const bf16x8*>(sB + r * 128 + sl * 16);
            }
#pragma unroll
            for (int m = 0; m < 4; ++m)
#pragma unroll
                for (int n = 0; n < 4; ++n)
                    acc[m][n] = __builtin_amdgcn_mfma_f32_16x16x32_bf16(af[m], bg[n], acc[m][n], 0, 0, 0);
        }
        __syncthreads();   // reads of tile u done before next GLL overwrite
    }

    // ---- fused LSTM epilogue; n-frag index IS the gate, j = (bx*2+wn)*16+l15
    const int jj = (bx * 2 + wn) * 16 + l15;
    const float bf_ = bF[jj], bi_ = bI[jj], bo_ = bO[jj], bc_ = bC[jj];
    const int rbase = by * 128 + wm * 64 + l16 * 4;
#pragma unroll
    for (int m = 0; m < 4; ++m) {
#pragma unroll
        for (int e = 0; e < 4; ++e) {
            int row = rbase + m * 16 + e;
            size_t idx = (size_t)row * 512 + jj;
            float fg = fast_sigmoid(acc[m][0][e] + bf_);
            float ig = fast_sigmoid(acc[m][1][e] + bi_);
            float og = fast_sigmoid(acc[m][2][e] + bo_);
            float cg = fast_tanh(acc[m][3][e] + bc_);
            float cs = cell[idx];
            float nc = fg * cs + ig * cg;
            float nh = og * fast_tanh(nc);
            out_cell[idx] = nc;
            out_hid[idx]  = nh;
            hid_bf[idx]   = (bf16_t)nh;
        }
    }
}

// ---------------- output GEMM: out = hid @ V^T + vb (verbatim r5) ----------------
__global__ void gemm_out(const bf16_t* __restrict__ Ah,   // [16384][512]
                         const bf16_t* __restrict__ V,    // [512][512]
                         const float* __restrict__ vb,
                         float* __restrict__ out) {
    constexpr int K = 512;
    const int tid  = threadIdx.x;
    const int lane = tid & 63;
    const int wid  = tid >> 6;
    const int wm   = wid >> 1;
    const int wn   = wid & 1;
    const int w  = blockIdx.y * 4 + blockIdx.x;
    const int s  = (w & 7) * 64 + (w >> 3);
    const int mtile = (s >> 2) * 128;
    const int ntile = (s & 3) * 128;

    __shared__ __align__(16) unsigned char sA[128 * 64];
    __shared__ __align__(16) unsigned char sB[128 * 64];

    f32x4 acc[4][4];  // [n-frag][m-frag]
#pragma unroll
    for (int n = 0; n < 4; ++n)
#pragma unroll
        for (int m = 0; m < 4; ++m) acc[n][m] = f32x4{0.f, 0.f, 0.f, 0.f};

    const bf16_t* gA[2]; const bf16_t* gB[2];
    unsigned ldsOff[2];
#pragma unroll
    for (int q = 0; q < 2; ++q) {
        int ch = q * 4 + wid;
        int r  = ch * 16 + (lane >> 2);
        int cphys = lane & 3;
        int clog  = cphys ^ ((r >> 1) & 3);
        gA[q] = Ah + (size_t)(mtile + r) * K + clog * 8;
        gB[q] = V  + (size_t)(ntile + r) * K + clog * 8;
        ldsOff[q] = (unsigned)ch * 1024;
    }

    for (int k0 = 0; k0 < K; k0 += 32) {
#pragma unroll
        for (int q = 0; q < 2; ++q) {
            GLL16(gA[q] + k0, sA + ldsOff[q]);
            GLL16(gB[q] + k0, sB + ldsOff[q]);
        }
        __syncthreads();

        bf16x8 af[4], bfv[4];
#pragma unroll
        for (int m = 0; m < 4; ++m) {
            int r = wm * 64 + m * 16 + (lane & 15);
            int c = (lane >> 4) ^ ((r >> 1) & 3);
            af[m] = *reinterpret_cast<const bf16x8*>(sA + r * 64 + c * 16);
        }
#pragma unroll
        for (int n = 0; n < 4; ++n) {
            int r = wn * 64 + n * 16 + (lane & 15);
            int c = (lane >> 4) ^ ((r >> 1) & 3);
            bfv[n] = *reinterpret_cast<const bf16x8*>(sB + r * 64 + c * 16);
        }
#pragma unroll
        for (int n = 0; n < 4; ++n)
#pragma unroll
            for (int m = 0; m < 4; ++m)
                acc[n][m] = __builtin_amdgcn_mfma_f32_16x16x32_bf16(af[m], bfv[n], acc[n][m], 0, 0, 0);
        __syncthreads();
    }

    const int cl = lane & 15;
#pragma unroll
    for (int n = 0; n < 4; ++n) {
        int coln = ntile + wn * 64 + n * 16 + cl;
        float b = vb[coln];
#pragma unroll
        for (int m = 0; m < 4; ++m) {
#pragma unroll
            for (int e = 0; e < 4; ++e) {
                int row = mtile + wm * 64 + m * 16 + (lane >> 4) * 4 + e;
                out[(size_t)row * 512 + coln] = acc[n][m][e] + b;
            }
        }
    }
}

extern "C" void kernel_launch(void* const* d_in, const int* in_sizes, int n_in,
                              void* d_out, int out_size, void* d_ws, size_t ws_size,
                              hipStream_t stream) {
    const float* inputs = (const float*)d_in[0];
    const float* cell   = (const float*)d_in[1];
    const float* hidden = (const float*)d_in[2];
    const float* Wf_w = (const float*)d_in[3];
    const float* Wf_b = (const float*)d_in[4];
    const float* Wi_w = (const float*)d_in[5];
    const float* Wi_b = (const float*)d_in[6];
    const float* Wc_w = (const float*)d_in[7];
    const float* Wc_b = (const float*)d_in[8];
    const float* Wo_w = (const float*)d_in[9];
    const float* Wo_b = (const float*)d_in[10];
    const float* V_w  = (const float*)d_in[11];
    const float* V_b  = (const float*)d_in[12];
    float* out = (float*)d_out;

    char* ws = (char*)d_ws;
    bf16_t* A_bf = (bf16_t*)(ws);                                  // 32 MB
    bf16_t* W_bf = (bf16_t*)(ws + 33554432);                       // 4 MB
    bf16_t* V_bf = (bf16_t*)(ws + 33554432 + 4194304);             // 0.5 MB
    bf16_t* h_bf = (bf16_t*)(ws + 33554432 + 4194304 + 524288);    // 16 MB

    pack_all<<<2048, 256, 0, stream>>>(inputs, hidden, Wf_w, Wi_w, Wo_w, Wc_w,
                                       V_w, A_bf, W_bf, V_bf);

    gemm_gates<<<2048, 256, 0, stream>>>(
        A_bf, W_bf, Wf_b, Wi_b, Wo_b, Wc_b, cell,
        out, out + (size_t)16384 * 512, h_bf);

    gemm_out<<<dim3(4, 128), 256, 0, stream>>>(
        h_bf, V_bf, V_b, out + (size_t)2 * 16384 * 512);
}